// Round 1
// baseline (232.047 us; speedup 1.0000x reference)
//
#include <hip/hip_runtime.h>
#include <hip/hip_bf16.h>
#include <cstdint>
#include <cstddef>

#define N_NODES 50000
#define DEG     24
#define NEDGE   (N_NODES*DEG)
#define RSZ     500
#define NDIM    64
#define FEATD   192

typedef short bf16x8 __attribute__((ext_vector_type(8)));
typedef float f32x4  __attribute__((ext_vector_type(4)));

__device__ __forceinline__ unsigned short f2bf(float f) {
    unsigned u = __builtin_bit_cast(unsigned, f);
    unsigned r = (u + 0x7fffu + ((u >> 16) & 1u)) >> 16;   // RNE
    return (unsigned short)r;
}
__device__ __forceinline__ float bf2f(unsigned short s) {
    unsigned u = ((unsigned)s) << 16;
    return __builtin_bit_cast(float, u);
}
__device__ __forceinline__ float fast_tanh(float x) {
    float e = __expf(2.f * x);
    return 1.f - 2.f / (e + 1.f);
}

// ---- P0: feats0 = tanh(features) -> outputs[:, 0:64] ------------------------
__global__ __launch_bounds__(256) void k_tanh_feat(const float* __restrict__ features,
                                                   float* __restrict__ outputs) {
    int t = blockIdx.x * 256 + threadIdx.x;        // 800000 threads, 4 elems each
    int idx4 = t * 4;
    int row = idx4 >> 6, col = idx4 & 63;
    float4 f = *reinterpret_cast<const float4*>(features + idx4);
    float4 o;
    o.x = fast_tanh(f.x); o.y = fast_tanh(f.y);
    o.z = fast_tanh(f.z); o.w = fast_tanh(f.w);
    *reinterpret_cast<float4*>(outputs + (size_t)row * FEATD + col) = o;
}

// ---- P1: reln = l2norm(rel_emb); attdot[l][r] = <reln[r], attn_k[l]> --------
__global__ __launch_bounds__(256) void k_rel_prep(const float* __restrict__ rel_emb,
                                                  const float* __restrict__ attn_k,
                                                  float* __restrict__ reln,
                                                  float* __restrict__ attdot) {
    int lane = threadIdx.x & 63;
    int row = blockIdx.x * 4 + (threadIdx.x >> 6);   // 125 blocks -> 500 rows
    float v = rel_emb[row * 64 + lane];
    float ss = v * v;
    for (int m = 1; m < 64; m <<= 1) ss += __shfl_xor(ss, m);
    float inv = 1.f / fmaxf(sqrtf(ss), 1e-12f);
    float rn = v * inv;
    reln[row * 64 + lane] = rn;
    float d0 = rn * attn_k[lane];
    float d1 = rn * attn_k[64 + lane];
    for (int m = 1; m < 64; m <<= 1) { d0 += __shfl_xor(d0, m); d1 += __shfl_xor(d1, m); }
    if (lane == 0) { attdot[row] = d0; attdot[RSZ + row] = d1; }
}

// ---- P2a: pn = l2norm(proxy) rows ------------------------------------------
__global__ __launch_bounds__(256) void k_proxy_norm(const float* __restrict__ proxy,
                                                    float* __restrict__ pn) {
    int lane = threadIdx.x & 63;
    int row = blockIdx.x * 4 + (threadIdx.x >> 6);   // 16 blocks -> 64 rows
    const float* p = proxy + (size_t)row * FEATD;
    float a = p[lane], b = p[64 + lane], c = p[128 + lane];
    float ss = a * a + b * b + c * c;
    for (int m = 1; m < 64; m <<= 1) ss += __shfl_xor(ss, m);
    float inv = 1.f / fmaxf(sqrtf(ss), 1e-12f);
    float* q = pn + (size_t)row * FEATD;
    q[lane] = a * inv; q[64 + lane] = b * inv; q[128 + lane] = c * inv;
}

// ---- PACK: B matrices into bf16 MFMA B-fragment order -----------------------
// B-frag for 16x16x32: lane holds B[k = (lane>>4)*8 + j][n = lane&15], j=0..7
__global__ __launch_bounds__(256) void k_pack(const float* __restrict__ pn,
                                              const float* __restrict__ proxy,
                                              const float* __restrict__ gate_w,
                                              unsigned short* __restrict__ B1,
                                              unsigned short* __restrict__ B2,
                                              unsigned short* __restrict__ B3) {
    int idx = blockIdx.x * 256 + threadIdx.x;        // 240 blocks = 61440 threads
    int j = idx & 7, lane = (idx >> 3) & 63;
    int t = idx >> 9;
    int lane16 = lane & 15, quad = lane >> 4;
    if (t < 24) {                 // B1: logits GEMM, Bmat[k][n] = pn[n][k]   (kt=t>>2, nt=t&3)
        int kt = t >> 2, nt = t & 3;
        int k = kt * 32 + quad * 8 + j, n = nt * 16 + lane16;
        B1[idx] = f2bf(pn[(size_t)n * FEATD + k]);
    } else if (t < 48) {          // B2: pa@proxy, Bmat[k][n] = proxy[k][n]
        int tt = t - 24, kt = tt / 12, nt = tt % 12;
        int k = kt * 32 + quad * 8 + j, n = nt * 16 + lane16;
        B2[idx - 12288] = f2bf(proxy[(size_t)k * FEATD + n]);
    } else {                      // B3: pf@gate_w^T, Bmat[k][n] = gate_w[n][k]
        int tt = t - 48, kt = tt / 12, nt = tt % 12;
        int k = kt * 32 + quad * 8 + j, n = nt * 16 + lane16;
        B3[idx - 24576] = f2bf(gate_w[(size_t)n * FEATD + k]);
    }
}

// ---- Layer: per-node attention aggregation ----------------------------------
// 16 lanes per node, 4 dims per lane; exact deg=24, contiguous edge segments.
__global__ __launch_bounds__(256) void k_layer(const int* __restrict__ src,
                                               const int* __restrict__ rel,
                                               const float* __restrict__ reln,
                                               const float* __restrict__ attdot_l,
                                               float* __restrict__ outputs,
                                               int colin, int colout) {
    int lane16 = threadIdx.x & 15;
    int node = blockIdx.x * 16 + (threadIdx.x >> 4);  // grid 3125 -> exactly 50000
    int ebase = node * DEG;
    const float* frow = outputs + colin;
    float ax = 0.f, ay = 0.f, az = 0.f, aw = 0.f, den = 0.f;
#pragma unroll 4
    for (int k = 0; k < DEG; k++) {
        int e = ebase + k;
        int s = src[e];
        int r = rel[e];
        float ex = __expf(attdot_l[r]);
        float4 tv = *reinterpret_cast<const float4*>(reln + (size_t)r * 64 + lane16 * 4);
        float4 nv = *reinterpret_cast<const float4*>(frow + (size_t)s * FEATD + lane16 * 4);
        float pd = tv.x * nv.x + tv.y * nv.y + tv.z * nv.z + tv.w * nv.w;
        pd += __shfl_xor(pd, 1); pd += __shfl_xor(pd, 2);
        pd += __shfl_xor(pd, 4); pd += __shfl_xor(pd, 8);
        float t1 = -2.f * pd * ex;          // acc += ex*(nv - 2*dot*tv)
        ax = fmaf(ex, nv.x, fmaf(t1, tv.x, ax));
        ay = fmaf(ex, nv.y, fmaf(t1, tv.y, ay));
        az = fmaf(ex, nv.z, fmaf(t1, tv.z, az));
        aw = fmaf(ex, nv.w, fmaf(t1, tv.w, aw));
        den += ex;
    }
    float id = 1.f / den;
    float4 o;
    o.x = fast_tanh(ax * id); o.y = fast_tanh(ay * id);
    o.z = fast_tanh(az * id); o.w = fast_tanh(aw * id);
    *reinterpret_cast<float4*>(outputs + (size_t)node * FEATD + colout + lane16 * 4) = o;
}

// ---- G1: logits = l2norm(o) @ pn^T (bf16 MFMA), fused row softmax -> pa -----
__global__ __launch_bounds__(256) void k_g1(const float* __restrict__ outputs,
                                            const unsigned short* __restrict__ B1,
                                            unsigned short* __restrict__ pa) {
    int lane = threadIdx.x & 63;
    int tile = blockIdx.x * 4 + (threadIdx.x >> 6);
    if (tile >= N_NODES / 16) return;
    int row0 = tile * 16, lane16 = lane & 15, quad = lane >> 4;
    const float* arow = outputs + (size_t)(row0 + lane16) * FEATD + quad * 8;
    bf16x8 af[6];
    float ss = 0.f;
#pragma unroll
    for (int kt = 0; kt < 6; kt++) {
        float4 p0 = *reinterpret_cast<const float4*>(arow + kt * 32);
        float4 p1 = *reinterpret_cast<const float4*>(arow + kt * 32 + 4);
        ss += p0.x * p0.x + p0.y * p0.y + p0.z * p0.z + p0.w * p0.w;
        ss += p1.x * p1.x + p1.y * p1.y + p1.z * p1.z + p1.w * p1.w;
        bf16x8 a;
        a[0] = (short)f2bf(p0.x); a[1] = (short)f2bf(p0.y);
        a[2] = (short)f2bf(p0.z); a[3] = (short)f2bf(p0.w);
        a[4] = (short)f2bf(p1.x); a[5] = (short)f2bf(p1.y);
        a[6] = (short)f2bf(p1.z); a[7] = (short)f2bf(p1.w);
        af[kt] = a;
    }
    ss += __shfl_xor(ss, 16); ss += __shfl_xor(ss, 32);   // full row sumsq at lane&15
    float inv = 1.f / fmaxf(sqrtf(ss), 1e-12f);
    f32x4 acc[4];
#pragma unroll
    for (int nt = 0; nt < 4; nt++) acc[nt] = (f32x4){0.f, 0.f, 0.f, 0.f};
#pragma unroll
    for (int kt = 0; kt < 6; kt++) {
#pragma unroll
        for (int nt = 0; nt < 4; nt++) {
            bf16x8 b = *reinterpret_cast<const bf16x8*>(B1 + ((size_t)(kt * 4 + nt) * 64 + lane) * 8);
            acc[nt] = __builtin_amdgcn_mfma_f32_16x16x32_bf16(af[kt], b, acc[nt], 0, 0, 0);
        }
    }
#pragma unroll
    for (int r = 0; r < 4; r++) {
        int rowloc = quad * 4 + r;                        // C-row of this reg
        float invr = __shfl(inv, rowloc);
        float v0 = acc[0][r] * invr, v1 = acc[1][r] * invr;
        float v2 = acc[2][r] * invr, v3 = acc[3][r] * invr;
        float m = fmaxf(fmaxf(v0, v1), fmaxf(v2, v3));
        m = fmaxf(m, __shfl_xor(m, 1)); m = fmaxf(m, __shfl_xor(m, 2));
        m = fmaxf(m, __shfl_xor(m, 4)); m = fmaxf(m, __shfl_xor(m, 8));
        float e0 = __expf(v0 - m), e1 = __expf(v1 - m);
        float e2 = __expf(v2 - m), e3 = __expf(v3 - m);
        float s = e0 + e1 + e2 + e3;
        s += __shfl_xor(s, 1); s += __shfl_xor(s, 2);
        s += __shfl_xor(s, 4); s += __shfl_xor(s, 8);
        float rs = 1.f / s;
        size_t base = (size_t)(row0 + rowloc) * 64 + lane16;
        pa[base]      = f2bf(e0 * rs);
        pa[base + 16] = f2bf(e1 * rs);
        pa[base + 32] = f2bf(e2 * rs);
        pa[base + 48] = f2bf(e3 * rs);
    }
}

// ---- G2: pf = o - pa @ proxy  (store bf16) ----------------------------------
__global__ __launch_bounds__(256) void k_g2(const unsigned short* __restrict__ pa,
                                            const unsigned short* __restrict__ B2,
                                            const float* __restrict__ outputs,
                                            unsigned short* __restrict__ pfb) {
    int lane = threadIdx.x & 63;
    int tile = blockIdx.x * 4 + (threadIdx.x >> 6);
    if (tile >= N_NODES / 16) return;
    int row0 = tile * 16, lane16 = lane & 15, quad = lane >> 4;
    f32x4 acc[12];
#pragma unroll
    for (int nt = 0; nt < 12; nt++) acc[nt] = (f32x4){0.f, 0.f, 0.f, 0.f};
#pragma unroll
    for (int kt = 0; kt < 2; kt++) {
        bf16x8 a = *reinterpret_cast<const bf16x8*>(pa + (size_t)(row0 + lane16) * 64 + kt * 32 + quad * 8);
#pragma unroll
        for (int nt = 0; nt < 12; nt++) {
            bf16x8 b = *reinterpret_cast<const bf16x8*>(B2 + ((size_t)(kt * 12 + nt) * 64 + lane) * 8);
            acc[nt] = __builtin_amdgcn_mfma_f32_16x16x32_bf16(a, b, acc[nt], 0, 0, 0);
        }
    }
#pragma unroll
    for (int nt = 0; nt < 12; nt++) {
#pragma unroll
        for (int r = 0; r < 4; r++) {
            int row = row0 + quad * 4 + r;
            size_t idx = (size_t)row * FEATD + nt * 16 + lane16;
            float o = outputs[idx];
            pfb[idx] = f2bf(o - acc[nt][r]);
        }
    }
}

// ---- G3: gate = sigmoid(pf @ gw^T + b); out = pf + gate*(o - pf) ------------
__global__ __launch_bounds__(256) void k_g3(const unsigned short* __restrict__ pfb,
                                            const unsigned short* __restrict__ B3,
                                            const float* __restrict__ outputs,
                                            const float* __restrict__ gate_b,
                                            float* __restrict__ dout) {
    int lane = threadIdx.x & 63;
    int tile = blockIdx.x * 4 + (threadIdx.x >> 6);
    if (tile >= N_NODES / 16) return;
    int row0 = tile * 16, lane16 = lane & 15, quad = lane >> 4;
    f32x4 acc[12];
#pragma unroll
    for (int nt = 0; nt < 12; nt++) acc[nt] = (f32x4){0.f, 0.f, 0.f, 0.f};
#pragma unroll
    for (int kt = 0; kt < 6; kt++) {
        bf16x8 a = *reinterpret_cast<const bf16x8*>(pfb + (size_t)(row0 + lane16) * FEATD + kt * 32 + quad * 8);
#pragma unroll
        for (int nt = 0; nt < 12; nt++) {
            bf16x8 b = *reinterpret_cast<const bf16x8*>(B3 + ((size_t)(kt * 12 + nt) * 64 + lane) * 8);
            acc[nt] = __builtin_amdgcn_mfma_f32_16x16x32_bf16(a, b, acc[nt], 0, 0, 0);
        }
    }
#pragma unroll
    for (int nt = 0; nt < 12; nt++) {
        float bias = gate_b[nt * 16 + lane16];
#pragma unroll
        for (int r = 0; r < 4; r++) {
            int row = row0 + quad * 4 + r;
            size_t idx = (size_t)row * FEATD + nt * 16 + lane16;
            float z = acc[nt][r] + bias;
            float g = 1.f / (1.f + __expf(-z));
            float o = outputs[idx];
            float pf = bf2f(pfb[idx]);
            dout[idx] = pf + g * (o - pf);
        }
    }
}

extern "C" void kernel_launch(void* const* d_in, const int* in_sizes, int n_in,
                              void* d_out, int out_size, void* d_ws, size_t ws_size,
                              hipStream_t stream) {
    (void)in_sizes; (void)n_in; (void)out_size; (void)ws_size;
    const float* features = (const float*)d_in[0];
    const float* rel_emb  = (const float*)d_in[1];
    const float* proxy    = (const float*)d_in[2];
    const float* gate_w   = (const float*)d_in[3];
    const float* gate_b   = (const float*)d_in[4];
    const float* attn_k   = (const float*)d_in[5];
    const int*   adj      = (const int*)d_in[6];
    const int*   r_index  = (const int*)d_in[7];
    // d_in[8] (r_val) unused: positive scale cancels under l2norm; r_index[0]==arange(E).

    // workspace carve (all 16B-aligned by construction)
    float* outputs = (float*)d_ws;                          // N*192 fp32
    float* reln    = outputs + (size_t)N_NODES * FEATD;     // 500*64
    float* attdot  = reln + RSZ * 64;                       // 2*500
    float* pn      = attdot + 2 * RSZ;                      // 64*192
    unsigned short* B1  = (unsigned short*)(pn + 64 * FEATD);  // 12288
    unsigned short* B2  = B1 + 12288;                          // 12288
    unsigned short* B3  = B2 + 12288;                          // 36864
    unsigned short* pa  = B3 + 36864;                          // N*64 bf16
    unsigned short* pfb = pa + (size_t)N_NODES * 64;           // N*192 bf16

    const int* src = adj + NEDGE;       // adj[1]
    const int* rel = r_index + NEDGE;   // r_index[1]

    k_tanh_feat <<<dim3(3125), dim3(256), 0, stream>>>(features, outputs);
    k_rel_prep  <<<dim3(125),  dim3(256), 0, stream>>>(rel_emb, attn_k, reln, attdot);
    k_proxy_norm<<<dim3(16),   dim3(256), 0, stream>>>(proxy, pn);
    k_pack      <<<dim3(240),  dim3(256), 0, stream>>>(pn, proxy, gate_w, B1, B2, B3);
    k_layer     <<<dim3(3125), dim3(256), 0, stream>>>(src, rel, reln, attdot,       outputs, 0,  64);
    k_layer     <<<dim3(3125), dim3(256), 0, stream>>>(src, rel, reln, attdot + RSZ, outputs, 64, 128);
    k_g1        <<<dim3(782),  dim3(256), 0, stream>>>(outputs, B1, pa);
    k_g2        <<<dim3(782),  dim3(256), 0, stream>>>(pa, B2, outputs, pfb);
    k_g3        <<<dim3(782),  dim3(256), 0, stream>>>(pfb, B3, outputs, gate_b, (float*)d_out);
}

// Round 2
// 227.402 us; speedup vs baseline: 1.0204x; 1.0204x over previous
//
#include <hip/hip_runtime.h>
#include <hip/hip_bf16.h>
#include <cstdint>
#include <cstddef>

#define N_NODES 50000
#define DEG     24
#define NEDGE   (N_NODES*DEG)
#define RSZ     500
#define NDIM    64
#define FEATD   192

// LDS row stride (shorts) for the 16x200 per-wave transpose buffer.
// 200*2=400B: 16B-aligned for b128, and 400/4=100 ≡ 4 (mod 32) spreads banks.
#define LSTR    200

typedef short bf16x8 __attribute__((ext_vector_type(8)));
typedef float f32x4  __attribute__((ext_vector_type(4)));

__device__ __forceinline__ unsigned short f2bf(float f) {
    unsigned u = __builtin_bit_cast(unsigned, f);
    unsigned r = (u + 0x7fffu + ((u >> 16) & 1u)) >> 16;   // RNE
    return (unsigned short)r;
}
__device__ __forceinline__ float bf2f(unsigned short s) {
    unsigned u = ((unsigned)s) << 16;
    return __builtin_bit_cast(float, u);
}
__device__ __forceinline__ float fast_tanh(float x) {
    float e = __expf(2.f * x);
    return 1.f - 2.f / (e + 1.f);
}

// ---- PREP (fused): tanh(features) | l2norm(rel)+exp(attdot) | 1/||proxy_n|| |
//                    pack B1/B2/B3 into bf16 MFMA B-fragment order.
// Block ranges: [0,3125) tanh, [3125,3250) rel, [3250,3266) pninv, [3266,3506) pack.
__global__ __launch_bounds__(256) void k_prep(const float* __restrict__ features,
                                              const float* __restrict__ rel_emb,
                                              const float* __restrict__ attn_k,
                                              const float* __restrict__ proxy,
                                              const float* __restrict__ gate_w,
                                              float* __restrict__ outputs,
                                              float* __restrict__ reln,
                                              float* __restrict__ expdot,
                                              float* __restrict__ pninv,
                                              unsigned short* __restrict__ B1,
                                              unsigned short* __restrict__ B2,
                                              unsigned short* __restrict__ B3) {
    int b = blockIdx.x;
    if (b < 3125) {
        // feats0 = tanh(features) -> outputs[:, 0:64]
        int t = b * 256 + threadIdx.x;             // 800000 threads, 4 elems each
        int idx4 = t * 4;
        int row = idx4 >> 6, col = idx4 & 63;
        float4 f = *reinterpret_cast<const float4*>(features + idx4);
        float4 o;
        o.x = fast_tanh(f.x); o.y = fast_tanh(f.y);
        o.z = fast_tanh(f.z); o.w = fast_tanh(f.w);
        *reinterpret_cast<float4*>(outputs + (size_t)row * FEATD + col) = o;
    } else if (b < 3250) {
        // reln = l2norm(rel_emb); expdot[l][r] = exp(<reln[r], attn_k[l]>)
        int lane = threadIdx.x & 63;
        int row = (b - 3125) * 4 + (threadIdx.x >> 6);   // 500 rows
        float v = rel_emb[row * 64 + lane];
        float ss = v * v;
        for (int m = 1; m < 64; m <<= 1) ss += __shfl_xor(ss, m);
        float inv = 1.f / fmaxf(sqrtf(ss), 1e-12f);
        float rn = v * inv;
        reln[row * 64 + lane] = rn;
        float d0 = rn * attn_k[lane];
        float d1 = rn * attn_k[64 + lane];
        for (int m = 1; m < 64; m <<= 1) { d0 += __shfl_xor(d0, m); d1 += __shfl_xor(d1, m); }
        if (lane == 0) { expdot[row] = __expf(d0); expdot[RSZ + row] = __expf(d1); }
    } else if (b < 3266) {
        // pninv[n] = 1/||proxy[n]||
        int lane = threadIdx.x & 63;
        int row = (b - 3250) * 4 + (threadIdx.x >> 6);   // 64 rows
        const float* p = proxy + (size_t)row * FEATD;
        float a = p[lane], bb = p[64 + lane], c = p[128 + lane];
        float ss = a * a + bb * bb + c * c;
        for (int m = 1; m < 64; m <<= 1) ss += __shfl_xor(ss, m);
        if (lane == 0) pninv[row] = 1.f / fmaxf(sqrtf(ss), 1e-12f);
    } else {
        // pack: B-frag for 16x16x32: lane holds B[k=(lane>>4)*8+j][n=lane&15], j=0..7
        int idx = (b - 3266) * 256 + threadIdx.x;        // 61440 threads
        int j = idx & 7, lane = (idx >> 3) & 63;
        int t = idx >> 9;
        int lane16 = lane & 15, quad = lane >> 4;
        if (t < 24) {                 // B1: logits GEMM, Bmat[k][n] = proxy[n][k] (raw; pninv applied later)
            int kt = t >> 2, nt = t & 3;
            int k = kt * 32 + quad * 8 + j, n = nt * 16 + lane16;
            B1[idx] = f2bf(proxy[(size_t)n * FEATD + k]);
        } else if (t < 48) {          // B2: pa@proxy, Bmat[k][n] = proxy[k][n]
            int tt = t - 24, kt = tt / 12, nt = tt % 12;
            int k = kt * 32 + quad * 8 + j, n = nt * 16 + lane16;
            B2[idx - 12288] = f2bf(proxy[(size_t)k * FEATD + n]);
        } else {                      // B3: pf@gate_w^T, Bmat[k][n] = gate_w[n][k]
            int tt = t - 48, kt = tt / 12, nt = tt % 12;
            int k = kt * 32 + quad * 8 + j, n = nt * 16 + lane16;
            B3[idx - 24576] = f2bf(gate_w[(size_t)n * FEATD + k]);
        }
    }
}

// ---- Layer: per-node attention aggregation ----------------------------------
// 16 lanes per node, 4 dims per lane; exact deg=24, contiguous edge segments.
__global__ __launch_bounds__(256) void k_layer(const int* __restrict__ src,
                                               const int* __restrict__ rel,
                                               const float* __restrict__ reln,
                                               const float* __restrict__ expdot_l,
                                               float* __restrict__ outputs,
                                               int colin, int colout) {
    int lane16 = threadIdx.x & 15;
    int node = blockIdx.x * 16 + (threadIdx.x >> 4);  // grid 3125 -> exactly 50000
    int ebase = node * DEG;
    const float* frow = outputs + colin;
    // Preload all edge indices: breaks the idx-load -> gather dependent chain.
    int sArr[DEG], rArr[DEG];
#pragma unroll
    for (int k = 0; k < DEG; k++) { sArr[k] = src[ebase + k]; rArr[k] = rel[ebase + k]; }
    float ax = 0.f, ay = 0.f, az = 0.f, aw = 0.f, den = 0.f;
#pragma unroll 8
    for (int k = 0; k < DEG; k++) {
        int s = sArr[k];
        int r = rArr[k];
        float ex = expdot_l[r];
        float4 tv = *reinterpret_cast<const float4*>(reln + (size_t)r * 64 + lane16 * 4);
        float4 nv = *reinterpret_cast<const float4*>(frow + (size_t)s * FEATD + lane16 * 4);
        float pd = tv.x * nv.x + tv.y * nv.y + tv.z * nv.z + tv.w * nv.w;
        pd += __shfl_xor(pd, 1); pd += __shfl_xor(pd, 2);
        pd += __shfl_xor(pd, 4); pd += __shfl_xor(pd, 8);
        float t1 = -2.f * pd * ex;          // acc += ex*(nv - 2*dot*tv)
        ax = fmaf(ex, nv.x, fmaf(t1, tv.x, ax));
        ay = fmaf(ex, nv.y, fmaf(t1, tv.y, ay));
        az = fmaf(ex, nv.z, fmaf(t1, tv.z, az));
        aw = fmaf(ex, nv.w, fmaf(t1, tv.w, aw));
        den += ex;
    }
    float id = 1.f / den;
    float4 o;
    o.x = fast_tanh(ax * id); o.y = fast_tanh(ay * id);
    o.z = fast_tanh(az * id); o.w = fast_tanh(aw * id);
    *reinterpret_cast<float4*>(outputs + (size_t)node * FEATD + colout + lane16 * 4) = o;
}

// ---- GATE (fused G1+G2+G3) --------------------------------------------------
// Per wave: 16-row tile. pa and pf round-trip through a private LDS buffer for
// the C-layout -> A-fragment transform. o held in registers across phases.
__global__ __launch_bounds__(256) void k_gate(const float* __restrict__ outputs,
                                              const unsigned short* __restrict__ B1,
                                              const unsigned short* __restrict__ B2,
                                              const unsigned short* __restrict__ B3,
                                              const float* __restrict__ pninv,
                                              const float* __restrict__ gate_b,
                                              float* __restrict__ dout) {
    __shared__ unsigned short lds[4][16 * LSTR];
    int wv = threadIdx.x >> 6, lane = threadIdx.x & 63;
    int tile = blockIdx.x * 4 + wv;
    if (tile > N_NODES / 16 - 1) tile = N_NODES / 16 - 1;  // dup work, identical writes
    int row0 = tile * 16, lane16 = lane & 15, quad = lane >> 4;
    unsigned short* L = lds[wv];

    // ---- Phase A: logits = (o/||o||) @ (proxy/||proxy||)^T, row softmax -> pa
    const float* arow = outputs + (size_t)(row0 + lane16) * FEATD + quad * 8;
    bf16x8 af[6];
    float ss = 0.f;
#pragma unroll
    for (int kt = 0; kt < 6; kt++) {
        float4 p0 = *reinterpret_cast<const float4*>(arow + kt * 32);
        float4 p1 = *reinterpret_cast<const float4*>(arow + kt * 32 + 4);
        ss += p0.x * p0.x + p0.y * p0.y + p0.z * p0.z + p0.w * p0.w;
        ss += p1.x * p1.x + p1.y * p1.y + p1.z * p1.z + p1.w * p1.w;
        bf16x8 a;
        a[0] = (short)f2bf(p0.x); a[1] = (short)f2bf(p0.y);
        a[2] = (short)f2bf(p0.z); a[3] = (short)f2bf(p0.w);
        a[4] = (short)f2bf(p1.x); a[5] = (short)f2bf(p1.y);
        a[6] = (short)f2bf(p1.z); a[7] = (short)f2bf(p1.w);
        af[kt] = a;
    }
    ss += __shfl_xor(ss, 16); ss += __shfl_xor(ss, 32);   // full row sumsq at lane&15
    float inv = 1.f / fmaxf(sqrtf(ss), 1e-12f);
    float pni[4];
#pragma unroll
    for (int nt = 0; nt < 4; nt++) pni[nt] = pninv[nt * 16 + lane16];
    f32x4 acc4[4];
#pragma unroll
    for (int nt = 0; nt < 4; nt++) acc4[nt] = (f32x4){0.f, 0.f, 0.f, 0.f};
#pragma unroll
    for (int kt = 0; kt < 6; kt++) {
#pragma unroll
        for (int nt = 0; nt < 4; nt++) {
            bf16x8 bfr = *reinterpret_cast<const bf16x8*>(B1 + ((size_t)(kt * 4 + nt) * 64 + lane) * 8);
            acc4[nt] = __builtin_amdgcn_mfma_f32_16x16x32_bf16(af[kt], bfr, acc4[nt], 0, 0, 0);
        }
    }
#pragma unroll
    for (int r = 0; r < 4; r++) {
        int rowloc = quad * 4 + r;                        // C-row of this reg
        float invr = __shfl(inv, rowloc);
        float v0 = acc4[0][r] * invr * pni[0], v1 = acc4[1][r] * invr * pni[1];
        float v2 = acc4[2][r] * invr * pni[2], v3 = acc4[3][r] * invr * pni[3];
        float m = fmaxf(fmaxf(v0, v1), fmaxf(v2, v3));
        m = fmaxf(m, __shfl_xor(m, 1)); m = fmaxf(m, __shfl_xor(m, 2));
        m = fmaxf(m, __shfl_xor(m, 4)); m = fmaxf(m, __shfl_xor(m, 8));
        float e0 = __expf(v0 - m), e1 = __expf(v1 - m);
        float e2 = __expf(v2 - m), e3 = __expf(v3 - m);
        float s = e0 + e1 + e2 + e3;
        s += __shfl_xor(s, 1); s += __shfl_xor(s, 2);
        s += __shfl_xor(s, 4); s += __shfl_xor(s, 8);
        float rs = 1.f / s;
        L[rowloc * LSTR + lane16]      = f2bf(e0 * rs);
        L[rowloc * LSTR + 16 + lane16] = f2bf(e1 * rs);
        L[rowloc * LSTR + 32 + lane16] = f2bf(e2 * rs);
        L[rowloc * LSTR + 48 + lane16] = f2bf(e3 * rs);
    }
    __syncthreads();

    // ---- Phase B: pf = o - pa @ proxy (pa A-frags from LDS); o kept in regs
    f32x4 acc[12];
#pragma unroll
    for (int nt = 0; nt < 12; nt++) acc[nt] = (f32x4){0.f, 0.f, 0.f, 0.f};
#pragma unroll
    for (int kt = 0; kt < 2; kt++) {
        bf16x8 a = *reinterpret_cast<const bf16x8*>(L + lane16 * LSTR + kt * 32 + quad * 8);
#pragma unroll
        for (int nt = 0; nt < 12; nt++) {
            bf16x8 bfr = *reinterpret_cast<const bf16x8*>(B2 + ((size_t)(kt * 12 + nt) * 64 + lane) * 8);
            acc[nt] = __builtin_amdgcn_mfma_f32_16x16x32_bf16(a, bfr, acc[nt], 0, 0, 0);
        }
    }
    float oreg[12][4];
#pragma unroll
    for (int nt = 0; nt < 12; nt++) {
#pragma unroll
        for (int r = 0; r < 4; r++) {
            int rowloc = quad * 4 + r;
            size_t idx = (size_t)(row0 + rowloc) * FEATD + nt * 16 + lane16;
            float o = outputs[idx];
            oreg[nt][r] = o;
            L[rowloc * LSTR + nt * 16 + lane16] = f2bf(o - acc[nt][r]);
        }
    }
    __syncthreads();

    // ---- Phase C: z = pf @ gate_w^T (pf A-frags from LDS)
#pragma unroll
    for (int nt = 0; nt < 12; nt++) acc[nt] = (f32x4){0.f, 0.f, 0.f, 0.f};
#pragma unroll
    for (int kt = 0; kt < 6; kt++) {
        bf16x8 a = *reinterpret_cast<const bf16x8*>(L + lane16 * LSTR + kt * 32 + quad * 8);
#pragma unroll
        for (int nt = 0; nt < 12; nt++) {
            bf16x8 bfr = *reinterpret_cast<const bf16x8*>(B3 + ((size_t)(kt * 12 + nt) * 64 + lane) * 8);
            acc[nt] = __builtin_amdgcn_mfma_f32_16x16x32_bf16(a, bfr, acc[nt], 0, 0, 0);
        }
    }

    // ---- Phase D: gate = sigmoid(z + b); out = pf + gate*(o - pf)
#pragma unroll
    for (int nt = 0; nt < 12; nt++) {
        float bias = gate_b[nt * 16 + lane16];
#pragma unroll
        for (int r = 0; r < 4; r++) {
            int rowloc = quad * 4 + r;
            size_t idx = (size_t)(row0 + rowloc) * FEATD + nt * 16 + lane16;
            float z = acc[nt][r] + bias;
            float g = 1.f / (1.f + __expf(-z));
            float pf = bf2f(L[rowloc * LSTR + nt * 16 + lane16]);
            dout[idx] = pf + g * (oreg[nt][r] - pf);
        }
    }
}

extern "C" void kernel_launch(void* const* d_in, const int* in_sizes, int n_in,
                              void* d_out, int out_size, void* d_ws, size_t ws_size,
                              hipStream_t stream) {
    (void)in_sizes; (void)n_in; (void)out_size; (void)ws_size;
    const float* features = (const float*)d_in[0];
    const float* rel_emb  = (const float*)d_in[1];
    const float* proxy    = (const float*)d_in[2];
    const float* gate_w   = (const float*)d_in[3];
    const float* gate_b   = (const float*)d_in[4];
    const float* attn_k   = (const float*)d_in[5];
    const int*   adj      = (const int*)d_in[6];
    const int*   r_index  = (const int*)d_in[7];
    // d_in[8] (r_val) unused: positive scale cancels under l2norm; r_index[0]==arange(E).

    // workspace carve (all 16B-aligned by construction)
    float* outputs = (float*)d_ws;                          // N*192 fp32
    float* reln    = outputs + (size_t)N_NODES * FEATD;     // 500*64
    float* expdot  = reln + RSZ * 64;                       // 2*500
    float* pninv   = expdot + 2 * RSZ;                      // 64
    unsigned short* B1 = (unsigned short*)(pninv + 64);     // 12288
    unsigned short* B2 = B1 + 12288;                        // 12288
    unsigned short* B3 = B2 + 12288;                        // 36864

    const int* src = adj + NEDGE;       // adj[1]
    const int* rel = r_index + NEDGE;   // r_index[1]

    k_prep  <<<dim3(3506), dim3(256), 0, stream>>>(features, rel_emb, attn_k, proxy, gate_w,
                                                   outputs, reln, expdot, pninv, B1, B2, B3);
    k_layer <<<dim3(3125), dim3(256), 0, stream>>>(src, rel, reln, expdot,       outputs, 0,  64);
    k_layer <<<dim3(3125), dim3(256), 0, stream>>>(src, rel, reln, expdot + RSZ, outputs, 64, 128);
    k_gate  <<<dim3(782),  dim3(256), 0, stream>>>(outputs, B1, B2, B3, pninv, gate_b, (float*)d_out);
}

// Round 3
// 205.186 us; speedup vs baseline: 1.1309x; 1.1083x over previous
//
#include <hip/hip_runtime.h>
#include <hip/hip_bf16.h>
#include <cstdint>
#include <cstddef>

#define N_NODES 50000
#define DEG     24
#define NEDGE   (N_NODES*DEG)
#define RSZ     500
#define NDIM    64
#define FEATD   192

// LDS row stride (shorts) for the 16x200 per-wave transpose buffer.
#define LSTR    200

// k_layer grid: 32 nodes/block (8 lanes x 8 dims per node), 1563 logical blocks,
// padded to 1568 = 8*196 for the XCD swizzle.
#define LGRID   1568
#define LCHUNK  196

typedef short bf16x8 __attribute__((ext_vector_type(8)));
typedef float f32x4  __attribute__((ext_vector_type(4)));

__device__ __forceinline__ unsigned short f2bf(float f) {
    unsigned u = __builtin_bit_cast(unsigned, f);
    unsigned r = (u + 0x7fffu + ((u >> 16) & 1u)) >> 16;   // RNE
    return (unsigned short)r;
}
__device__ __forceinline__ float bf2f(unsigned short s) {
    unsigned u = ((unsigned)s) << 16;
    return __builtin_bit_cast(float, u);
}
__device__ __forceinline__ float fast_tanh(float x) {
    float e = __expf(2.f * x);
    return 1.f - 2.f / (e + 1.f);
}

// ---- PREP (fused): tanh(features) -> outputs[:,0:64] + compact fin0 |
//      l2norm(rel)+exp(attdot) | 1/||proxy_n|| | pack B1/B2/B3 | pack edges.
// Block ranges: [0,3125) tanh, [3125,3250) rel, [3250,3266) pninv,
//               [3266,3506) packB, [3506,4678) packE.
__global__ __launch_bounds__(256) void k_prep(const float* __restrict__ features,
                                              const float* __restrict__ rel_emb,
                                              const float* __restrict__ attn_k,
                                              const float* __restrict__ proxy,
                                              const float* __restrict__ gate_w,
                                              const int* __restrict__ src,
                                              const int* __restrict__ rel,
                                              float* __restrict__ outputs,
                                              float* __restrict__ fin0,
                                              float* __restrict__ reln,
                                              float* __restrict__ expdot,
                                              float* __restrict__ pninv,
                                              unsigned short* __restrict__ B1,
                                              unsigned short* __restrict__ B2,
                                              unsigned short* __restrict__ B3,
                                              unsigned int* __restrict__ pedge) {
    int b = blockIdx.x;
    if (b < 3125) {
        // feats0 = tanh(features) -> outputs[:, 0:64] and compact fin0[N][64]
        int t = b * 256 + threadIdx.x;             // 800000 threads, 4 elems each
        int idx4 = t * 4;
        int row = idx4 >> 6, col = idx4 & 63;
        float4 f = *reinterpret_cast<const float4*>(features + idx4);
        float4 o;
        o.x = fast_tanh(f.x); o.y = fast_tanh(f.y);
        o.z = fast_tanh(f.z); o.w = fast_tanh(f.w);
        *reinterpret_cast<float4*>(outputs + (size_t)row * FEATD + col) = o;
        *reinterpret_cast<float4*>(fin0 + idx4) = o;
    } else if (b < 3250) {
        // reln = l2norm(rel_emb); expdot[l][r] = exp(<reln[r], attn_k[l]>)
        int lane = threadIdx.x & 63;
        int row = (b - 3125) * 4 + (threadIdx.x >> 6);   // 500 rows
        float v = rel_emb[row * 64 + lane];
        float ss = v * v;
        for (int m = 1; m < 64; m <<= 1) ss += __shfl_xor(ss, m);
        float inv = 1.f / fmaxf(sqrtf(ss), 1e-12f);
        float rn = v * inv;
        reln[row * 64 + lane] = rn;
        float d0 = rn * attn_k[lane];
        float d1 = rn * attn_k[64 + lane];
        for (int m = 1; m < 64; m <<= 1) { d0 += __shfl_xor(d0, m); d1 += __shfl_xor(d1, m); }
        if (lane == 0) { expdot[row] = __expf(d0); expdot[RSZ + row] = __expf(d1); }
    } else if (b < 3266) {
        // pninv[n] = 1/||proxy[n]||
        int lane = threadIdx.x & 63;
        int row = (b - 3250) * 4 + (threadIdx.x >> 6);   // 64 rows
        const float* p = proxy + (size_t)row * FEATD;
        float a = p[lane], bb = p[64 + lane], c = p[128 + lane];
        float ss = a * a + bb * bb + c * c;
        for (int m = 1; m < 64; m <<= 1) ss += __shfl_xor(ss, m);
        if (lane == 0) pninv[row] = 1.f / fmaxf(sqrtf(ss), 1e-12f);
    } else if (b < 3506) {
        // pack: B-frag for 16x16x32: lane holds B[k=(lane>>4)*8+j][n=lane&15], j=0..7
        int idx = (b - 3266) * 256 + threadIdx.x;        // 61440 threads
        int j = idx & 7, lane = (idx >> 3) & 63;
        int t = idx >> 9;
        int lane16 = lane & 15, quad = lane >> 4;
        if (t < 24) {                 // B1: Bmat[k][n] = proxy[n][k] (raw; pninv applied later)
            int kt = t >> 2, nt = t & 3;
            int k = kt * 32 + quad * 8 + j, n = nt * 16 + lane16;
            B1[idx] = f2bf(proxy[(size_t)n * FEATD + k]);
        } else if (t < 48) {          // B2: pa@proxy, Bmat[k][n] = proxy[k][n]
            int tt = t - 24, kt = tt / 12, nt = tt % 12;
            int k = kt * 32 + quad * 8 + j, n = nt * 16 + lane16;
            B2[idx - 12288] = f2bf(proxy[(size_t)k * FEATD + n]);
        } else {                      // B3: pf@gate_w^T, Bmat[k][n] = gate_w[n][k]
            int tt = t - 48, kt = tt / 12, nt = tt % 12;
            int k = kt * 32 + quad * 8 + j, n = nt * 16 + lane16;
            B3[idx - 24576] = f2bf(gate_w[(size_t)n * FEATD + k]);
        }
    } else {
        // pack edges: pe = s | (r<<16)   (s < 65536, r < 512)
        int t = (b - 3506) * 256 + threadIdx.x;          // 300032 threads, need 300000
        if (t < NEDGE / 4) {
            int4 s4 = *reinterpret_cast<const int4*>(src + t * 4);
            int4 r4 = *reinterpret_cast<const int4*>(rel + t * 4);
            uint4 o;
            o.x = (unsigned)s4.x | ((unsigned)r4.x << 16);
            o.y = (unsigned)s4.y | ((unsigned)r4.y << 16);
            o.z = (unsigned)s4.z | ((unsigned)r4.z << 16);
            o.w = (unsigned)s4.w | ((unsigned)r4.w << 16);
            *reinterpret_cast<uint4*>(pedge + t * 4) = o;
        }
    }
}

// ---- Layer: per-node attention aggregation ----------------------------------
// 8 lanes per node, 8 dims per lane. Compact fp32 fin[N][64] input.
// XCD swizzle: physical block b -> XCD b%8; remap so each XCD gets a
// contiguous node range (its gather window then lives in its own L2).
__global__ __launch_bounds__(256) void k_layer(const unsigned int* __restrict__ pedge,
                                               const float* __restrict__ reln,
                                               const float* __restrict__ expdot_l,
                                               const float* __restrict__ fin,
                                               float* __restrict__ fout,
                                               float* __restrict__ outputs,
                                               int colout) {
    int b = blockIdx.x;
    int lb = (b & 7) * LCHUNK + (b >> 3);
    int lane8 = threadIdx.x & 7;
    int node = lb * 32 + (threadIdx.x >> 3);
    if (node >= N_NODES) return;
    int ebase = node * DEG;
    // Preload all packed edge indices: no idx-load -> gather dependence.
    unsigned pk[DEG];
#pragma unroll
    for (int k = 0; k < DEG; k++) pk[k] = pedge[ebase + k];
    float a0 = 0.f, a1 = 0.f, a2 = 0.f, a3 = 0.f;
    float a4 = 0.f, a5 = 0.f, a6 = 0.f, a7 = 0.f, den = 0.f;
#pragma unroll 4
    for (int k = 0; k < DEG; k++) {
        unsigned p = pk[k];
        int s = p & 0xFFFF;
        int r = p >> 16;
        float ex = expdot_l[r];
        const float* tp = reln + (size_t)r * 64 + lane8 * 8;
        const float* np = fin + (size_t)s * 64 + lane8 * 8;
        float4 t0 = *reinterpret_cast<const float4*>(tp);
        float4 t1v = *reinterpret_cast<const float4*>(tp + 4);
        float4 n0 = *reinterpret_cast<const float4*>(np);
        float4 n1v = *reinterpret_cast<const float4*>(np + 4);
        float pd = t0.x * n0.x + t0.y * n0.y + t0.z * n0.z + t0.w * n0.w
                 + t1v.x * n1v.x + t1v.y * n1v.y + t1v.z * n1v.z + t1v.w * n1v.w;
        pd += __shfl_xor(pd, 1); pd += __shfl_xor(pd, 2); pd += __shfl_xor(pd, 4);
        float t1 = -2.f * pd * ex;          // acc += ex*(nv - 2*dot*tv)
        a0 = fmaf(ex, n0.x, fmaf(t1, t0.x, a0));
        a1 = fmaf(ex, n0.y, fmaf(t1, t0.y, a1));
        a2 = fmaf(ex, n0.z, fmaf(t1, t0.z, a2));
        a3 = fmaf(ex, n0.w, fmaf(t1, t0.w, a3));
        a4 = fmaf(ex, n1v.x, fmaf(t1, t1v.x, a4));
        a5 = fmaf(ex, n1v.y, fmaf(t1, t1v.y, a5));
        a6 = fmaf(ex, n1v.z, fmaf(t1, t1v.z, a6));
        a7 = fmaf(ex, n1v.w, fmaf(t1, t1v.w, a7));
        den += ex;
    }
    float id = 1.f / den;
    float4 o0, o1;
    o0.x = fast_tanh(a0 * id); o0.y = fast_tanh(a1 * id);
    o0.z = fast_tanh(a2 * id); o0.w = fast_tanh(a3 * id);
    o1.x = fast_tanh(a4 * id); o1.y = fast_tanh(a5 * id);
    o1.z = fast_tanh(a6 * id); o1.w = fast_tanh(a7 * id);
    float* orow = outputs + (size_t)node * FEATD + colout + lane8 * 8;
    *reinterpret_cast<float4*>(orow) = o0;
    *reinterpret_cast<float4*>(orow + 4) = o1;
    if (fout) {
        float* f = fout + (size_t)node * 64 + lane8 * 8;
        *reinterpret_cast<float4*>(f) = o0;
        *reinterpret_cast<float4*>(f + 4) = o1;
    }
}

// ---- GATE (fused G1+G2+G3) --------------------------------------------------
__global__ __launch_bounds__(256) void k_gate(const float* __restrict__ outputs,
                                              const unsigned short* __restrict__ B1,
                                              const unsigned short* __restrict__ B2,
                                              const unsigned short* __restrict__ B3,
                                              const float* __restrict__ pninv,
                                              const float* __restrict__ gate_b,
                                              float* __restrict__ dout) {
    __shared__ unsigned short lds[4][16 * LSTR];
    int wv = threadIdx.x >> 6, lane = threadIdx.x & 63;
    int tile = blockIdx.x * 4 + wv;
    if (tile > N_NODES / 16 - 1) tile = N_NODES / 16 - 1;  // dup work, identical writes
    int row0 = tile * 16, lane16 = lane & 15, quad = lane >> 4;
    unsigned short* L = lds[wv];

    // ---- Phase A: logits = (o/||o||) @ (proxy/||proxy||)^T, row softmax -> pa
    const float* arow = outputs + (size_t)(row0 + lane16) * FEATD + quad * 8;
    bf16x8 af[6];
    float ss = 0.f;
#pragma unroll
    for (int kt = 0; kt < 6; kt++) {
        float4 p0 = *reinterpret_cast<const float4*>(arow + kt * 32);
        float4 p1 = *reinterpret_cast<const float4*>(arow + kt * 32 + 4);
        ss += p0.x * p0.x + p0.y * p0.y + p0.z * p0.z + p0.w * p0.w;
        ss += p1.x * p1.x + p1.y * p1.y + p1.z * p1.z + p1.w * p1.w;
        bf16x8 a;
        a[0] = (short)f2bf(p0.x); a[1] = (short)f2bf(p0.y);
        a[2] = (short)f2bf(p0.z); a[3] = (short)f2bf(p0.w);
        a[4] = (short)f2bf(p1.x); a[5] = (short)f2bf(p1.y);
        a[6] = (short)f2bf(p1.z); a[7] = (short)f2bf(p1.w);
        af[kt] = a;
    }
    ss += __shfl_xor(ss, 16); ss += __shfl_xor(ss, 32);   // full row sumsq at lane&15
    float inv = 1.f / fmaxf(sqrtf(ss), 1e-12f);
    float pni[4];
#pragma unroll
    for (int nt = 0; nt < 4; nt++) pni[nt] = pninv[nt * 16 + lane16];
    f32x4 acc4[4];
#pragma unroll
    for (int nt = 0; nt < 4; nt++) acc4[nt] = (f32x4){0.f, 0.f, 0.f, 0.f};
#pragma unroll
    for (int kt = 0; kt < 6; kt++) {
#pragma unroll
        for (int nt = 0; nt < 4; nt++) {
            bf16x8 bfr = *reinterpret_cast<const bf16x8*>(B1 + ((size_t)(kt * 4 + nt) * 64 + lane) * 8);
            acc4[nt] = __builtin_amdgcn_mfma_f32_16x16x32_bf16(af[kt], bfr, acc4[nt], 0, 0, 0);
        }
    }
#pragma unroll
    for (int r = 0; r < 4; r++) {
        int rowloc = quad * 4 + r;                        // C-row of this reg
        float invr = __shfl(inv, rowloc);
        float v0 = acc4[0][r] * invr * pni[0], v1 = acc4[1][r] * invr * pni[1];
        float v2 = acc4[2][r] * invr * pni[2], v3 = acc4[3][r] * invr * pni[3];
        float m = fmaxf(fmaxf(v0, v1), fmaxf(v2, v3));
        m = fmaxf(m, __shfl_xor(m, 1)); m = fmaxf(m, __shfl_xor(m, 2));
        m = fmaxf(m, __shfl_xor(m, 4)); m = fmaxf(m, __shfl_xor(m, 8));
        float e0 = __expf(v0 - m), e1 = __expf(v1 - m);
        float e2 = __expf(v2 - m), e3 = __expf(v3 - m);
        float s = e0 + e1 + e2 + e3;
        s += __shfl_xor(s, 1); s += __shfl_xor(s, 2);
        s += __shfl_xor(s, 4); s += __shfl_xor(s, 8);
        float rs = 1.f / s;
        L[rowloc * LSTR + lane16]      = f2bf(e0 * rs);
        L[rowloc * LSTR + 16 + lane16] = f2bf(e1 * rs);
        L[rowloc * LSTR + 32 + lane16] = f2bf(e2 * rs);
        L[rowloc * LSTR + 48 + lane16] = f2bf(e3 * rs);
    }
    __syncthreads();

    // ---- Phase B: pf = o - pa @ proxy (pa A-frags from LDS); o kept in regs
    f32x4 acc[12];
#pragma unroll
    for (int nt = 0; nt < 12; nt++) acc[nt] = (f32x4){0.f, 0.f, 0.f, 0.f};
#pragma unroll
    for (int kt = 0; kt < 2; kt++) {
        bf16x8 a = *reinterpret_cast<const bf16x8*>(L + lane16 * LSTR + kt * 32 + quad * 8);
#pragma unroll
        for (int nt = 0; nt < 12; nt++) {
            bf16x8 bfr = *reinterpret_cast<const bf16x8*>(B2 + ((size_t)(kt * 12 + nt) * 64 + lane) * 8);
            acc[nt] = __builtin_amdgcn_mfma_f32_16x16x32_bf16(a, bfr, acc[nt], 0, 0, 0);
        }
    }
    float oreg[12][4];
#pragma unroll
    for (int nt = 0; nt < 12; nt++) {
#pragma unroll
        for (int r = 0; r < 4; r++) {
            int rowloc = quad * 4 + r;
            size_t idx = (size_t)(row0 + rowloc) * FEATD + nt * 16 + lane16;
            float o = outputs[idx];
            oreg[nt][r] = o;
            L[rowloc * LSTR + nt * 16 + lane16] = f2bf(o - acc[nt][r]);
        }
    }
    __syncthreads();

    // ---- Phase C: z = pf @ gate_w^T (pf A-frags from LDS)
#pragma unroll
    for (int nt = 0; nt < 12; nt++) acc[nt] = (f32x4){0.f, 0.f, 0.f, 0.f};
#pragma unroll
    for (int kt = 0; kt < 6; kt++) {
        bf16x8 a = *reinterpret_cast<const bf16x8*>(L + lane16 * LSTR + kt * 32 + quad * 8);
#pragma unroll
        for (int nt = 0; nt < 12; nt++) {
            bf16x8 bfr = *reinterpret_cast<const bf16x8*>(B3 + ((size_t)(kt * 12 + nt) * 64 + lane) * 8);
            acc[nt] = __builtin_amdgcn_mfma_f32_16x16x32_bf16(a, bfr, acc[nt], 0, 0, 0);
        }
    }

    // ---- Phase D: gate = sigmoid(z + b); out = pf + gate*(o - pf)
#pragma unroll
    for (int nt = 0; nt < 12; nt++) {
        float bias = gate_b[nt * 16 + lane16];
#pragma unroll
        for (int r = 0; r < 4; r++) {
            int rowloc = quad * 4 + r;
            size_t idx = (size_t)(row0 + rowloc) * FEATD + nt * 16 + lane16;
            float z = acc[nt][r] + bias;
            float g = 1.f / (1.f + __expf(-z));
            float pf = bf2f(L[rowloc * LSTR + nt * 16 + lane16]);
            dout[idx] = pf + g * (oreg[nt][r] - pf);
        }
    }
}

extern "C" void kernel_launch(void* const* d_in, const int* in_sizes, int n_in,
                              void* d_out, int out_size, void* d_ws, size_t ws_size,
                              hipStream_t stream) {
    (void)in_sizes; (void)n_in; (void)out_size; (void)ws_size;
    const float* features = (const float*)d_in[0];
    const float* rel_emb  = (const float*)d_in[1];
    const float* proxy    = (const float*)d_in[2];
    const float* gate_w   = (const float*)d_in[3];
    const float* gate_b   = (const float*)d_in[4];
    const float* attn_k   = (const float*)d_in[5];
    const int*   adj      = (const int*)d_in[6];
    const int*   r_index  = (const int*)d_in[7];
    // d_in[8] (r_val) unused: positive scale cancels under l2norm; r_index[0]==arange(E).

    // workspace carve (all 16B-aligned by construction)
    float* outputs = (float*)d_ws;                          // N*192 fp32
    float* fin0    = outputs + (size_t)N_NODES * FEATD;     // N*64 fp32 (layer-1 input)
    float* fin1    = fin0 + (size_t)N_NODES * 64;           // N*64 fp32 (layer-2 input)
    float* reln    = fin1 + (size_t)N_NODES * 64;           // 500*64
    float* expdot  = reln + RSZ * 64;                       // 2*500
    float* pninv   = expdot + 2 * RSZ;                      // 64
    unsigned short* B1 = (unsigned short*)(pninv + 64);     // 12288
    unsigned short* B2 = B1 + 12288;                        // 12288
    unsigned short* B3 = B2 + 12288;                        // 36864
    unsigned int* pedge = (unsigned int*)(B3 + 36864);      // NEDGE u32

    const int* src = adj + NEDGE;       // adj[1]
    const int* rel = r_index + NEDGE;   // r_index[1]

    k_prep  <<<dim3(4678), dim3(256), 0, stream>>>(features, rel_emb, attn_k, proxy, gate_w,
                                                   src, rel, outputs, fin0, reln, expdot,
                                                   pninv, B1, B2, B3, pedge);
    k_layer <<<dim3(LGRID), dim3(256), 0, stream>>>(pedge, reln, expdot,       fin0, fin1,    outputs, 64);
    k_layer <<<dim3(LGRID), dim3(256), 0, stream>>>(pedge, reln, expdot + RSZ, fin1, nullptr, outputs, 128);
    k_gate  <<<dim3(782),  dim3(256), 0, stream>>>(outputs, B1, B2, B3, pninv, gate_b, (float*)d_out);
}